// Round 10
// baseline (102.744 us; speedup 1.0000x reference)
//
#include <hip/hip_runtime.h>
#include <hip/hip_fp16.h>
#include <math.h>

// (B,Tq,Tk,U) = (32,1024,1024,256), f32 in/out.
// ROUND 10 = INSTRUMENTED: sk body x8 reps inside the kernel (so the sk
// dispatch exceeds the 39us ws-poison fills and surfaces in rocprof top-5
// WITH its counters), pv launched x2. Output identical to round 9.
//   T_sk  = sk_dispatch_dur / 8   (direct)
//   T_pv  = (total10 - 49.9) - 7*T_sk
#define NB 32
#define TQ 1024
#define TK 1024
#define UD 256

typedef __attribute__((ext_vector_type(8))) _Float16 f16x8;
typedef __attribute__((ext_vector_type(4))) _Float16 f16x4;
typedef __attribute__((ext_vector_type(4))) float f32x4;

__device__ __forceinline__ float fast_tanh(float x) {
  const float e = __expf(2.0f * x);
  return 1.0f - 2.0f / (e + 1.0f);
}

// ---------------------------------------------------------------------------
// K0: Wq f32 -> f16, k-slot-major: wq16t[ks][u][8] (ks = k>>3).
// ---------------------------------------------------------------------------
__global__ __launch_bounds__(256) void cvt_wq_kernel(
    const float* __restrict__ Wq, _Float16* __restrict__ wq16t) {
  const int idx = blockIdx.x * 256 + threadIdx.x;  // 8192
  const int u = idx >> 5;
  const int ks = idx & 31;
  const float4 w0 = *reinterpret_cast<const float4*>(Wq + u * UD + ks * 8);
  const float4 w1 = *reinterpret_cast<const float4*>(Wq + u * UD + ks * 8 + 4);
  f16x8 h;
  h[0] = (_Float16)w0.x; h[1] = (_Float16)w0.y;
  h[2] = (_Float16)w0.z; h[3] = (_Float16)w0.w;
  h[4] = (_Float16)w1.x; h[5] = (_Float16)w1.y;
  h[6] = (_Float16)w1.z; h[7] = (_Float16)w1.w;
  *reinterpret_cast<f16x8*>(wq16t + ((size_t)ks * 256 + u) * 8) = h;
}

// ---------------------------------------------------------------------------
// K1: identical body to round 9, but repeated REP times (acc re-zeroed each
// rep -> same output; barriers prevent hoisting/CSE). Epilogue outside.
// ---------------------------------------------------------------------------
#define REP 8

__global__ __launch_bounds__(512, 4) void sk_mfma_kernel(
    const float* __restrict__ key, const _Float16* __restrict__ wq16t,
    const float* __restrict__ v, float* __restrict__ sk) {
  __shared__ _Float16 At[32 * 64 * 8];     // 32 KB
  __shared__ _Float16 Bt[2][4 * 256 * 8];  // 2 x 16 KB

  const int tid = threadIdx.x;
  const int lane = tid & 63;
  const int wid = tid >> 6;  // 0..7
  const int wr = wid >> 2;   // 0..1 (row half)
  const int wc = wid & 3;    // 0..3 (u quarter)
  const int lx = lane & 15;
  const int lg = lane >> 4;
  const int row0 = blockIdx.x * 64;

  f32x4 acc[2][4];

#pragma unroll 1
  for (int rep = 0; rep < REP; ++rep) {
#pragma unroll
    for (int m = 0; m < 2; ++m)
#pragma unroll
      for (int n = 0; n < 4; ++n) acc[m][n] = (f32x4){0.f, 0.f, 0.f, 0.f};

    // ---- stage A: wave wid loads rows wid*8..+7, 1 KB contiguous each ----
    {
      const int ks = lane >> 1;  // 0..31
      const int jh = lane & 1;   // 16-B half
#pragma unroll
      for (int i = 0; i < 8; ++i) {
        const int r = wid * 8 + i;
        const float4 a = *reinterpret_cast<const float4*>(
            key + (size_t)(row0 + r) * UD + lane * 4);
        f16x4 h;
        h[0] = (_Float16)a.x; h[1] = (_Float16)a.y;
        h[2] = (_Float16)a.z; h[3] = (_Float16)a.w;
        const int rs = r ^ (ks & 7);
        *reinterpret_cast<f16x4*>(At + ((ks * 64 + rs) * 8 + jh * 4)) = h;
      }
    }

    // ---- stage B phase 0 (linear 16 KB copy) ----
#pragma unroll
    for (int it = 0; it < 2; ++it) {
      const int f = tid + it * 512;
      *(reinterpret_cast<f16x8*>(Bt[0]) + f) =
          *(reinterpret_cast<const f16x8*>(wq16t) + f);
    }
    __syncthreads();

#pragma unroll
    for (int p = 0; p < 8; ++p) {
      const int cur = p & 1;
      if (p < 7) {
#pragma unroll
        for (int it = 0; it < 2; ++it) {
          const int f = tid + it * 512;
          *(reinterpret_cast<f16x8*>(Bt[cur ^ 1]) + f) =
              *(reinterpret_cast<const f16x8*>(wq16t + (size_t)(p + 1) * 8192) +
                f);
        }
      }
      const int ksg = p * 4 + lg;
      f16x8 af[2], bf[4];
#pragma unroll
      for (int m = 0; m < 2; ++m) {
        const int row = wr * 32 + m * 16 + lx;
        const int rs = row ^ (ksg & 7);
        af[m] = *reinterpret_cast<const f16x8*>(At + (ksg * 64 + rs) * 8);
      }
#pragma unroll
      for (int n = 0; n < 4; ++n) {
        const int u = wc * 64 + n * 16 + lx;
        bf[n] = *reinterpret_cast<const f16x8*>(Bt[cur] + (lg * 256 + u) * 8);
      }
#pragma unroll
      for (int m = 0; m < 2; ++m)
#pragma unroll
        for (int n = 0; n < 4; ++n)
          acc[m][n] = __builtin_amdgcn_mfma_f32_16x16x32_f16(
              af[m], bf[n], acc[m][n], 0, 0, 0);
      __syncthreads();
    }
  }

  // ---- epilogue: tanh, dot v, shfl-reduce over lx, LDS-reduce over wc ----
  float vv[4];
#pragma unroll
  for (int n = 0; n < 4; ++n) vv[n] = v[wc * 64 + n * 16 + lx];

  float* red = (float*)At;
  float part[2][4];
#pragma unroll
  for (int m = 0; m < 2; ++m)
#pragma unroll
    for (int r = 0; r < 4; ++r) part[m][r] = 0.f;
#pragma unroll
  for (int m = 0; m < 2; ++m)
#pragma unroll
    for (int n = 0; n < 4; ++n)
#pragma unroll
      for (int r = 0; r < 4; ++r)
        part[m][r] += vv[n] * fast_tanh(acc[m][n][r]);

#pragma unroll
  for (int m = 0; m < 2; ++m)
#pragma unroll
    for (int r = 0; r < 4; ++r) {
      float s = part[m][r];
      s += __shfl_xor(s, 1);
      s += __shfl_xor(s, 2);
      s += __shfl_xor(s, 4);
      s += __shfl_xor(s, 8);
      if (lx == 0) red[(wr * 32 + m * 16 + lg * 4 + r) * 4 + wc] = s;
    }
  __syncthreads();
  if (tid < 64) {
    sk[row0 + tid] = red[tid * 4 + 0] + red[tid * 4 + 1] + red[tid * 4 + 2] +
                     red[tid * 4 + 3];
  }
}

// ---------------------------------------------------------------------------
// K2: fused softmax + PV partial (identical to round 9).
// ---------------------------------------------------------------------------
__global__ __launch_bounds__(256) void pv_kernel(
    const float* __restrict__ sk, const int* __restrict__ vlen,
    const float* __restrict__ value, float* __restrict__ part) {
  const int b = blockIdx.x >> 4;
  const int ch = blockIdx.x & 15;
  const int tid = threadIdx.x;
  const int vl = vlen[b];
  __shared__ float wbuf[64];
  __shared__ float red4[8];
  const float* skb = sk + b * TK;

  if (vl == 0) {
    if (tid < 64) wbuf[tid] = 1.0f / (float)TK;
  } else {
    float m = -1e30f;
#pragma unroll
    for (int idx = 0; idx < 4; ++idx) {
      const int k = tid + idx * 256;
      if (k < vl) m = fmaxf(m, skb[k]);
    }
    for (int off = 1; off < 64; off <<= 1) m = fmaxf(m, __shfl_xor(m, off));
    if ((tid & 63) == 0) red4[tid >> 6] = m;
    __syncthreads();
    m = fmaxf(fmaxf(red4[0], red4[1]), fmaxf(red4[2], red4[3]));
    float zs = 0.f;
#pragma unroll
    for (int idx = 0; idx < 4; ++idx) {
      const int k = tid + idx * 256;
      zs += (k < vl) ? __expf(skb[k] - m) : 0.f;
    }
    for (int off = 1; off < 64; off <<= 1) zs += __shfl_xor(zs, off);
    if ((tid & 63) == 0) red4[4 + (tid >> 6)] = zs;
    __syncthreads();
    const float rz = 1.0f / (red4[4] + red4[5] + red4[6] + red4[7]);
    if (tid < 64) {
      const int k = ch * 64 + tid;
      wbuf[tid] = (k < vl) ? __expf(skb[k] - m) * rz : 0.f;
    }
  }
  __syncthreads();

  const int d = tid;
  const float* vb = value + ((size_t)b * TK + ch * 64) * UD;
  float acc = 0.f;
#pragma unroll 8
  for (int k = 0; k < 64; ++k)
    acc = fmaf(wbuf[k], vb[(size_t)k * UD + d], acc);
  part[(size_t)(b * 16 + ch) * UD + d] = acc;
}

// ---------------------------------------------------------------------------
// K3: reduce 16 partials -> out_row, broadcast over 64 q rows/block.
// ---------------------------------------------------------------------------
__global__ __launch_bounds__(256) void bcast_kernel(
    const float* __restrict__ part, float* __restrict__ out) {
  const int b = blockIdx.x >> 4;
  const int qc = blockIdx.x & 15;
  const int tid = threadIdx.x;
  const int qoff = tid >> 6;      // 0..3
  const int dd = (tid & 63) * 4;  // 0..252

  float4 s = make_float4(0.f, 0.f, 0.f, 0.f);
#pragma unroll
  for (int c = 0; c < 16; ++c) {
    const float4 p = *reinterpret_cast<const float4*>(
        &part[(size_t)(b * 16 + c) * UD + dd]);
    s.x += p.x; s.y += p.y; s.z += p.z; s.w += p.w;
  }

  float* ob = out + (size_t)b * TQ * UD + (size_t)qc * 64 * UD;
#pragma unroll 4
  for (int q4 = 0; q4 < 16; ++q4) {
    *reinterpret_cast<float4*>(&ob[(size_t)(q4 * 4 + qoff) * UD + dd]) = s;
  }
}

// ---------------------------------------------------------------------------
extern "C" void kernel_launch(void* const* d_in, const int* in_sizes, int n_in,
                              void* d_out, int out_size, void* d_ws,
                              size_t ws_size, hipStream_t stream) {
  // inputs: 0 query, 1 key, 2 value, 3 valid_length, 4 W_k, 5 W_q, 6 v
  const float* key = (const float*)d_in[1];
  const float* value = (const float*)d_in[2];
  const int* vlen = (const int*)d_in[3];
  const float* Wq = (const float*)d_in[5];
  const float* v = (const float*)d_in[6];
  float* out = (float*)d_out;

  char* ws = (char*)d_ws;
  _Float16* wq16t = (_Float16*)(ws);    // 128 KB (k-slot-major f16 Wq)
  float* sk = (float*)(ws + 131072);    // 128 KB
  float* part = (float*)(ws + 262144);  // 512 KB

  cvt_wq_kernel<<<32, 256, 0, stream>>>(Wq, wq16t);
  sk_mfma_kernel<<<(NB * TK) / 64, 512, 0, stream>>>(key, wq16t, v, sk);
  pv_kernel<<<NB * 16, 256, 0, stream>>>(sk, vlen, value, part);
  pv_kernel<<<NB * 16, 256, 0, stream>>>(sk, vlen, value, part);
  bcast_kernel<<<NB * 16, 256, 0, stream>>>(part, out);
}

// Round 11
// 49.009 us; speedup vs baseline: 2.0964x; 2.0964x over previous
//
#include <hip/hip_runtime.h>
#include <hip/hip_fp16.h>
#include <math.h>

// (B,Tq,Tk,U) = (32,1024,1024,256), f32 in/out.
#define NB 32
#define TQ 1024
#define TK 1024
#define UD 256

typedef __attribute__((ext_vector_type(8))) _Float16 f16x8;
typedef __attribute__((ext_vector_type(4))) _Float16 f16x4;
typedef __attribute__((ext_vector_type(4))) float f32x4;

__device__ __forceinline__ float fast_tanh(float x) {
  const float e = __expf(2.0f * x);
  return 1.0f - 2.0f / (e + 1.0f);
}

// ---------------------------------------------------------------------------
// K0: Wq f32 -> f16, k-slot-major: wq16t[ks][u][8] (ks = k>>3).
// ---------------------------------------------------------------------------
__global__ __launch_bounds__(256) void cvt_wq_kernel(
    const float* __restrict__ Wq, _Float16* __restrict__ wq16t) {
  const int idx = blockIdx.x * 256 + threadIdx.x;  // 8192
  const int u = idx >> 5;
  const int ks = idx & 31;
  const float4 w0 = *reinterpret_cast<const float4*>(Wq + u * UD + ks * 8);
  const float4 w1 = *reinterpret_cast<const float4*>(Wq + u * UD + ks * 8 + 4);
  f16x8 h;
  h[0] = (_Float16)w0.x; h[1] = (_Float16)w0.y;
  h[2] = (_Float16)w0.z; h[3] = (_Float16)w0.w;
  h[4] = (_Float16)w1.x; h[5] = (_Float16)w1.y;
  h[6] = (_Float16)w1.z; h[7] = (_Float16)w1.w;
  *reinterpret_cast<f16x8*>(wq16t + ((size_t)ks * 256 + u) * 8) = h;
}

// ---------------------------------------------------------------------------
// K1: sk[r] = sum_u v[u] * tanh( sum_c key[r,c] * Wq[u,c] )   (MFMA f16)
// 512 blocks x 512 thr (8 waves, 2M x 4N). 64 rows x 256 u per block.
// MLP-focused restructure of round 9:
//   A: 8 float4 row-loads batched into a register array (8 in flight/wave),
//      then cvt -> XOR-swizzled LDS At (32 KB), staged once.
//   B: per phase, NEXT phase's 16 KB loaded to regs at phase top (T14),
//      ds_written AFTER the MFMA cluster; double-buffered Bt (2x16 KB).
// LDS 64 KB -> 2 blocks/CU; VGPR budget ~116 < 128 cap of (512,4).
// ---------------------------------------------------------------------------
__global__ __launch_bounds__(512, 4) void sk_mfma_kernel(
    const float* __restrict__ key, const _Float16* __restrict__ wq16t,
    const float* __restrict__ v, float* __restrict__ sk) {
  __shared__ _Float16 At[32 * 64 * 8];     // 32 KB
  __shared__ _Float16 Bt[2][4 * 256 * 8];  // 2 x 16 KB

  const int tid = threadIdx.x;
  const int lane = tid & 63;
  const int wid = tid >> 6;  // 0..7
  const int wr = wid >> 2;   // 0..1 (row half)
  const int wc = wid & 3;    // 0..3 (u quarter)
  const int lx = lane & 15;
  const int lg = lane >> 4;
  const int row0 = blockIdx.x * 64;

  // ---- A-stage: batch all 8 row-loads (1 KB contiguous per wave-load) ----
  float4 areg[8];
#pragma unroll
  for (int i = 0; i < 8; ++i) {
    const int r = wid * 8 + i;
    areg[i] = *reinterpret_cast<const float4*>(key + (size_t)(row0 + r) * UD +
                                               lane * 4);
  }
  // ---- B phase-0 loads (linear 16 KB) ----
  f16x8 b0a = reinterpret_cast<const f16x8*>(wq16t)[tid];
  f16x8 b0b = reinterpret_cast<const f16x8*>(wq16t)[tid + 512];

  // ---- A cvt + swizzled LDS write ----
  {
    const int ks = lane >> 1;  // 0..31
    const int jh = lane & 1;   // 16-B half
#pragma unroll
    for (int i = 0; i < 8; ++i) {
      const int r = wid * 8 + i;
      f16x4 h;
      h[0] = (_Float16)areg[i].x; h[1] = (_Float16)areg[i].y;
      h[2] = (_Float16)areg[i].z; h[3] = (_Float16)areg[i].w;
      const int rs = r ^ (ks & 7);
      *reinterpret_cast<f16x4*>(At + ((ks * 64 + rs) * 8 + jh * 4)) = h;
    }
  }
  // ---- B phase-0 LDS write ----
  reinterpret_cast<f16x8*>(Bt[0])[tid] = b0a;
  reinterpret_cast<f16x8*>(Bt[0])[tid + 512] = b0b;
  __syncthreads();

  f32x4 acc[2][4];
#pragma unroll
  for (int m = 0; m < 2; ++m)
#pragma unroll
    for (int n = 0; n < 4; ++n) acc[m][n] = (f32x4){0.f, 0.f, 0.f, 0.f};

#pragma unroll
  for (int p = 0; p < 8; ++p) {
    const int cur = p & 1;
    // T14 split: issue next-phase global loads NOW...
    f16x8 breg0, breg1;
    if (p < 7) {
      const f16x8* src =
          reinterpret_cast<const f16x8*>(wq16t + (size_t)(p + 1) * 8192);
      breg0 = src[tid];
      breg1 = src[tid + 512];
    }
    // ...compute current phase while they fly...
    const int ksg = p * 4 + lg;
    f16x8 af[2], bf[4];
#pragma unroll
    for (int m = 0; m < 2; ++m) {
      const int row = wr * 32 + m * 16 + lx;
      const int rs = row ^ (ksg & 7);
      af[m] = *reinterpret_cast<const f16x8*>(At + (ksg * 64 + rs) * 8);
    }
#pragma unroll
    for (int n = 0; n < 4; ++n) {
      const int u = wc * 64 + n * 16 + lx;
      bf[n] = *reinterpret_cast<const f16x8*>(Bt[cur] + (lg * 256 + u) * 8);
    }
#pragma unroll
    for (int m = 0; m < 2; ++m)
#pragma unroll
      for (int n = 0; n < 4; ++n)
        acc[m][n] = __builtin_amdgcn_mfma_f32_16x16x32_f16(af[m], bf[n],
                                                           acc[m][n], 0, 0, 0);
    // ...then commit them to the buffer freed by the previous barrier.
    if (p < 7) {
      reinterpret_cast<f16x8*>(Bt[cur ^ 1])[tid] = breg0;
      reinterpret_cast<f16x8*>(Bt[cur ^ 1])[tid + 512] = breg1;
    }
    __syncthreads();
  }

  // ---- epilogue: tanh, dot v, shfl-reduce over lx, LDS-reduce over wc ----
  // acc[m][n] reg r: row = wr*32 + m*16 + lg*4 + r ; u = wc*64 + n*16 + lx
  float vv[4];
#pragma unroll
  for (int n = 0; n < 4; ++n) vv[n] = v[wc * 64 + n * 16 + lx];

  float* red = (float*)At;  // At free after final barrier
  float part[2][4];
#pragma unroll
  for (int m = 0; m < 2; ++m)
#pragma unroll
    for (int r = 0; r < 4; ++r) part[m][r] = 0.f;
#pragma unroll
  for (int m = 0; m < 2; ++m)
#pragma unroll
    for (int n = 0; n < 4; ++n)
#pragma unroll
      for (int r = 0; r < 4; ++r)
        part[m][r] += vv[n] * fast_tanh(acc[m][n][r]);

#pragma unroll
  for (int m = 0; m < 2; ++m)
#pragma unroll
    for (int r = 0; r < 4; ++r) {
      float s = part[m][r];
      s += __shfl_xor(s, 1);
      s += __shfl_xor(s, 2);
      s += __shfl_xor(s, 4);
      s += __shfl_xor(s, 8);
      if (lx == 0) red[(wr * 32 + m * 16 + lg * 4 + r) * 4 + wc] = s;
    }
  __syncthreads();
  if (tid < 64) {
    sk[row0 + tid] = red[tid * 4 + 0] + red[tid * 4 + 1] + red[tid * 4 + 2] +
                     red[tid * 4 + 3];
  }
}

// ---------------------------------------------------------------------------
// K2: fused softmax + PV partial (r1-proven contiguous pattern).
// ---------------------------------------------------------------------------
__global__ __launch_bounds__(256) void pv_kernel(
    const float* __restrict__ sk, const int* __restrict__ vlen,
    const float* __restrict__ value, float* __restrict__ part) {
  const int b = blockIdx.x >> 4;
  const int ch = blockIdx.x & 15;
  const int tid = threadIdx.x;
  const int vl = vlen[b];
  __shared__ float wbuf[64];
  __shared__ float red4[8];
  const float* skb = sk + b * TK;

  if (vl == 0) {  // uniform softmax over the constant-fill row
    if (tid < 64) wbuf[tid] = 1.0f / (float)TK;
  } else {
    float m = -1e30f;
#pragma unroll
    for (int idx = 0; idx < 4; ++idx) {
      const int k = tid + idx * 256;
      if (k < vl) m = fmaxf(m, skb[k]);
    }
    for (int off = 1; off < 64; off <<= 1) m = fmaxf(m, __shfl_xor(m, off));
    if ((tid & 63) == 0) red4[tid >> 6] = m;
    __syncthreads();
    m = fmaxf(fmaxf(red4[0], red4[1]), fmaxf(red4[2], red4[3]));
    float zs = 0.f;
#pragma unroll
    for (int idx = 0; idx < 4; ++idx) {
      const int k = tid + idx * 256;
      zs += (k < vl) ? __expf(skb[k] - m) : 0.f;
    }
    for (int off = 1; off < 64; off <<= 1) zs += __shfl_xor(zs, off);
    if ((tid & 63) == 0) red4[4 + (tid >> 6)] = zs;
    __syncthreads();
    const float rz = 1.0f / (red4[4] + red4[5] + red4[6] + red4[7]);
    if (tid < 64) {
      const int k = ch * 64 + tid;
      wbuf[tid] = (k < vl) ? __expf(skb[k] - m) * rz : 0.f;
    }
  }
  __syncthreads();

  const int d = tid;
  const float* vb = value + ((size_t)b * TK + ch * 64) * UD;
  float acc = 0.f;
#pragma unroll 8
  for (int k = 0; k < 64; ++k)
    acc = fmaf(wbuf[k], vb[(size_t)k * UD + d], acc);
  part[(size_t)(b * 16 + ch) * UD + d] = acc;
}

// ---------------------------------------------------------------------------
// K3: reduce 16 partials -> out_row, broadcast over 64 q rows/block.
// ---------------------------------------------------------------------------
__global__ __launch_bounds__(256) void bcast_kernel(
    const float* __restrict__ part, float* __restrict__ out) {
  const int b = blockIdx.x >> 4;
  const int qc = blockIdx.x & 15;
  const int tid = threadIdx.x;
  const int qoff = tid >> 6;      // 0..3
  const int dd = (tid & 63) * 4;  // 0..252

  float4 s = make_float4(0.f, 0.f, 0.f, 0.f);
#pragma unroll
  for (int c = 0; c < 16; ++c) {
    const float4 p = *reinterpret_cast<const float4*>(
        &part[(size_t)(b * 16 + c) * UD + dd]);
    s.x += p.x; s.y += p.y; s.z += p.z; s.w += p.w;
  }

  float* ob = out + (size_t)b * TQ * UD + (size_t)qc * 64 * UD;
#pragma unroll 4
  for (int q4 = 0; q4 < 16; ++q4) {
    *reinterpret_cast<float4*>(&ob[(size_t)(q4 * 4 + qoff) * UD + dd]) = s;
  }
}

// ---------------------------------------------------------------------------
extern "C" void kernel_launch(void* const* d_in, const int* in_sizes, int n_in,
                              void* d_out, int out_size, void* d_ws,
                              size_t ws_size, hipStream_t stream) {
  // inputs: 0 query, 1 key, 2 value, 3 valid_length, 4 W_k, 5 W_q, 6 v
  const float* key = (const float*)d_in[1];
  const float* value = (const float*)d_in[2];
  const int* vlen = (const int*)d_in[3];
  const float* Wq = (const float*)d_in[5];
  const float* v = (const float*)d_in[6];
  float* out = (float*)d_out;

  char* ws = (char*)d_ws;
  _Float16* wq16t = (_Float16*)(ws);    // 128 KB (k-slot-major f16 Wq)
  float* sk = (float*)(ws + 131072);    // 128 KB
  float* part = (float*)(ws + 262144);  // 512 KB

  cvt_wq_kernel<<<32, 256, 0, stream>>>(Wq, wq16t);
  sk_mfma_kernel<<<(NB * TK) / 64, 512, 0, stream>>>(key, wq16t, v, sk);
  pv_kernel<<<NB * 16, 256, 0, stream>>>(sk, vlen, value, part);
  bcast_kernel<<<NB * 16, 256, 0, stream>>>(part, out);
}